// Round 9
// baseline (629.066 us; speedup 1.0000x reference)
//
#include <hip/hip_runtime.h>
#include <hip/hip_bf16.h>
#include <cstdint>
#include <cstddef>

#define HWPIX 65536
#define IMGW 256
#define CDIM 192
#define C3 576
#define NBATCH 4
#define NHEADS 8
#define CPH 24
#define KP 104   // padded K pitch for proj MFMA LDS tiles
#define KQ 96    // linear K pitch for qkv (global_load_lds, source-swizzled)

using bf16 = __hip_bfloat16;
typedef __attribute__((ext_vector_type(8))) short short8;
typedef __attribute__((ext_vector_type(4))) float f32x4;
typedef unsigned int u32;
typedef unsigned short u16;

__device__ __forceinline__ float b2f(bf16 v) { return __bfloat162float(v); }
__device__ __forceinline__ bf16 f2b(float v) { return __float2bfloat16(v); }
__device__ __forceinline__ float bu2f(u16 h) { return __uint_as_float((u32)h << 16); }
__device__ __forceinline__ u16 f2bu(float x) {
    bf16 h = __float2bfloat16(x);
    return *reinterpret_cast<u16*>(&h);
}
__device__ __forceinline__ u32 pack2(float a, float b) {
    return (u32)f2bu(a) | ((u32)f2bu(b) << 16);
}
__device__ __forceinline__ void gload_lds16(const u16* gsrc, u16* ldst) {
    __builtin_amdgcn_global_load_lds(
        (const __attribute__((address_space(1))) void*)gsrc,
        (__attribute__((address_space(3))) void*)ldst, 16, 0, 0);
}

// ---------------------------------------------------------------------------
// Convert weights f32 -> bf16 (u16).
// ---------------------------------------------------------------------------
__global__ __launch_bounds__(256) void prep_weights(
    const float* __restrict__ W, u16* __restrict__ Wb, int n)
{
    int i = blockIdx.x * 256 + threadIdx.x;
    if (i < n) Wb[i] = f2bu(W[i]);
}

// ---------------------------------------------------------------------------
// X f32 [b][k][p] -> Xt bf16 [b][p][k]  (one-time transpose+convert).
// ---------------------------------------------------------------------------
__global__ __launch_bounds__(256) void xprep_kernel(
    const float* __restrict__ X, u16* __restrict__ Xt)
{
    __shared__ float sX[CDIM * 68];
    const int b  = blockIdx.y;
    const int p0 = blockIdx.x * 64;
    const int tid = threadIdx.x;

#pragma unroll
    for (int i = 0; i < 12; ++i) {
        const int idx = tid + i * 256;        // 0..3071 float4s
        const int p4 = idx & 15, k = idx >> 4;
        const float4 v = *reinterpret_cast<const float4*>(
            X + ((size_t)b * CDIM + k) * HWPIX + p0 + p4 * 4);
        *reinterpret_cast<float4*>(&sX[k * 68 + p4 * 4]) = v;
    }
    __syncthreads();

    const int p = tid >> 2;          // 0..63
    const int seg = tid & 3;         // 0..3 (6 k-blocks each)
    u16* dst = Xt + ((size_t)b * HWPIX + p0 + p) * CDIM;
#pragma unroll
    for (int s = 0; s < 6; ++s) {
        const int blk = seg * 6 + s; // 0..23, 8 k each
        float f[8];
#pragma unroll
        for (int j = 0; j < 8; ++j) f[j] = sX[(blk * 8 + j) * 68 + p];
        uint4 ov;
        ov.x = pack2(f[0], f[1]);
        ov.y = pack2(f[2], f[3]);
        ov.z = pack2(f[4], f[5]);
        ov.w = pack2(f[6], f[7]);
        *reinterpret_cast<uint4*>(dst + blk * 8) = ov;
    }
}

// ---------------------------------------------------------------------------
// qkv 1x1 conv as bf16 MFMA GEMM.
// R8: staging via global_load_lds (async, no VGPR round-trip, linear LDS
// writes = conflict-free). Single 192-row arena (rows 0-63 = W, 64-191 = Xt),
// KQ=96 linear; bank-friendliness recovered with SOURCE-side XOR swizzle:
//   LDS[row][blk] = src[row][blk ^ ((row>>2)&3)], reads XOR the same way
//   (rows r,r+16,r+32,r+48 share the swizzle; blk^f stays in [0,12)).
// Fragment-read banks: exactly 8 dwords/bank per wave b128 read (0-conflict).
// Epilogue sOut stride 132 (66 dw = 2 mod 32 -> hk rows 8 banks apart).
// ---------------------------------------------------------------------------
__global__ __launch_bounds__(256, 4) void conv_qkv_mfma(
    const u16* __restrict__ Xt, const u16* __restrict__ Wb,
    const float* __restrict__ bias, bf16* __restrict__ Y)
{
    __shared__ alignas(16) u16 sAB[192 * KQ];   // 36864 B
    __shared__ float sBias[64];

    int lin = blockIdx.x;
    lin = (lin & 7) * (18432 / 8) + (lin >> 3);
    const int co_t = lin % 9;
    const int rest = lin / 9;
    const int p_t = rest & 511;
    const int b   = rest >> 9;
    const int co0 = co_t * 64;
    const int p0  = p_t * 128;

    const int tid  = threadIdx.x;
    const int wave = tid >> 6;
    const int lane = tid & 63;
    const int r  = lane & 15;
    const int hk = lane >> 4;

    if (tid < 64) sBias[tid] = bias[co0 + tid];

    f32x4 acc[4][2];
#pragma unroll
    for (int i = 0; i < 4; ++i)
#pragma unroll
        for (int j = 0; j < 2; ++j) acc[i][j] = (f32x4){0.f, 0.f, 0.f, 0.f};

#pragma unroll
    for (int c = 0; c < 2; ++c) {
        // ---- stage A+B: 192 rows x 96 k via global_load_lds (9 loads/wave).
        // wave w owns rows [48w, 48w+48); lane l of iter i fills LDS u16
        // offset w*4608 + i*512 + 8l  (HW: wave-uniform base + lane*16B).
        {
            u16* wbase = sAB + wave * 4608;
#pragma unroll
            for (int i = 0; i < 9; ++i) {
                const int m  = i * 64 + lane;          // 0..575
                const int gr = wave * 48 + m / 12;     // global row 0..191
                const int blk = m % 12;
                const int sblk = blk ^ ((gr >> 2) & 3);
                const u16* gsrc = (gr < 64)
                    ? (Wb + (size_t)(co0 + gr) * CDIM)
                    : (Xt + ((size_t)b * HWPIX + p0 + gr - 64) * CDIM);
                gload_lds16(gsrc + c * 96 + sblk * 8, wbase + i * 512);
            }
        }
        __syncthreads();

#pragma unroll
        for (int ks = 0; ks < 3; ++ks) {
            const int kb = ks * 4 + hk;                 // 16B block 0..11
            const int fA = (r >> 2) & 3;
            const u16* pA = &sAB[r * KQ + (kb ^ fA) * 8];
            const int rowb = 64 + wave * 32 + r;
            const int fB = (rowb >> 2) & 3;
            const u16* pB = &sAB[rowb * KQ + (kb ^ fB) * 8];
            const short8 a0 = *reinterpret_cast<const short8*>(pA);
            const short8 a1 = *reinterpret_cast<const short8*>(pA + 16 * KQ);
            const short8 a2 = *reinterpret_cast<const short8*>(pA + 32 * KQ);
            const short8 a3 = *reinterpret_cast<const short8*>(pA + 48 * KQ);
            const short8 b0 = *reinterpret_cast<const short8*>(pB);
            const short8 b1 = *reinterpret_cast<const short8*>(pB + 16 * KQ);
            acc[0][0] = __builtin_amdgcn_mfma_f32_16x16x32_bf16(a0, b0, acc[0][0], 0, 0, 0);
            acc[1][0] = __builtin_amdgcn_mfma_f32_16x16x32_bf16(a1, b0, acc[1][0], 0, 0, 0);
            acc[2][0] = __builtin_amdgcn_mfma_f32_16x16x32_bf16(a2, b0, acc[2][0], 0, 0, 0);
            acc[3][0] = __builtin_amdgcn_mfma_f32_16x16x32_bf16(a3, b0, acc[3][0], 0, 0, 0);
            acc[0][1] = __builtin_amdgcn_mfma_f32_16x16x32_bf16(a0, b1, acc[0][1], 0, 0, 0);
            acc[1][1] = __builtin_amdgcn_mfma_f32_16x16x32_bf16(a1, b1, acc[1][1], 0, 0, 0);
            acc[2][1] = __builtin_amdgcn_mfma_f32_16x16x32_bf16(a2, b1, acc[2][1], 0, 0, 0);
            acc[3][1] = __builtin_amdgcn_mfma_f32_16x16x32_bf16(a3, b1, acc[3][1], 0, 0, 0);
        }
        __syncthreads();
    }

    // ---- epilogue: acc -> bf16 LDS tile [64co][132] -> coalesced stores
#define OS2 132
    u16* sOut = sAB;   // reuse (post-barrier)
#pragma unroll
    for (int mf = 0; mf < 4; ++mf) {
#pragma unroll
        for (int j = 0; j < 4; ++j) {
            const int row = mf * 16 + hk * 4 + j;
            const float bs = sBias[row];
            sOut[row * OS2 + wave * 32 + r]      = f2bu(acc[mf][0][j] + bs);
            sOut[row * OS2 + wave * 32 + r + 16] = f2bu(acc[mf][1][j] + bs);
        }
    }
    __syncthreads();
#pragma unroll
    for (int i = 0; i < 4; ++i) {
        const int idx = tid + i * 256;
        const int row = idx >> 4, cq = idx & 15;
        const u16* src = &sOut[row * OS2 + cq * 8];
        const uint2 lo = *reinterpret_cast<const uint2*>(src);
        const uint2 hi = *reinterpret_cast<const uint2*>(src + 4);
        uint4 v = {lo.x, lo.y, hi.x, hi.y};
        *reinterpret_cast<uint4*>(
            &Y[((size_t)b * C3 + co0 + row) * HWPIX + p0 + cq * 8]) = v;
    }
}

// ---------------------------------------------------------------------------
// proj 1x1 conv as bf16 MFMA GEMM — bf16 osum [c][p] in (unchanged).
// ---------------------------------------------------------------------------
__global__ __launch_bounds__(256, 4) void conv_proj_mfma(
    const u16* __restrict__ X, const u16* __restrict__ Wb,
    const float* __restrict__ bias, float* __restrict__ Y)
{
    __shared__ alignas(16) u16 sA[64 * KP];
    __shared__ alignas(16) u16 sB[128 * KP];
    __shared__ float sBias[64];

    int lin = blockIdx.x;                       // nwg = 6144
    lin = (lin & 7) * (6144 / 8) + (lin >> 3);
    const int co_t = lin % 3;
    const int rest = lin / 3;
    const int p_t = rest & 511;
    const int b   = rest >> 9;
    const int co0 = co_t * 64;
    const int p0  = p_t * 128;

    const int tid  = threadIdx.x;
    const int wave = tid >> 6;
    const int lane = tid & 63;
    const int r  = lane & 15;
    const int hk = lane >> 4;

    if (tid < 64) sBias[tid] = bias[co0 + tid];

    f32x4 acc[4][2];
#pragma unroll
    for (int i = 0; i < 4; ++i)
#pragma unroll
        for (int j = 0; j < 2; ++j) acc[i][j] = (f32x4){0.f, 0.f, 0.f, 0.f};

    const int p4 = tid & 31;        // p-quad 0..31 (4 p each)
    const int kq = tid >> 5;        // 0..7 k-pair sub-index

#pragma unroll
    for (int c = 0; c < 2; ++c) {
        {
            int idx = tid;
#pragma unroll
            for (int i = 0; i < 3; ++i, idx += 256) {
                const int row = idx / 12, cv = idx % 12;
                const uint4 v = *reinterpret_cast<const uint4*>(
                    Wb + (size_t)(co0 + row) * CDIM + c * 96 + cv * 8);
                *reinterpret_cast<uint4*>(&sA[row * KP + cv * 8]) = v;
            }
        }
        {
            const u16* Xc = X + ((size_t)b * CDIM + c * 96) * HWPIX + p0;
#pragma unroll
            for (int i = 0; i < 6; ++i) {
                const int kp = kq + i * 8;            // 0..47
                const int k  = kp * 2;                // even
                const uint2 va = *reinterpret_cast<const uint2*>(
                    Xc + (size_t)k * HWPIX + p4 * 4);
                const uint2 vb = *reinterpret_cast<const uint2*>(
                    Xc + (size_t)(k + 1) * HWPIX + p4 * 4);
                const int col = (((kp >> 2) ^ (p4 & 3)) << 3) | (k & 7);
                const u32 w0 = (va.x & 0xffffu) | (vb.x << 16);
                const u32 w1 = (va.x >> 16)     | (vb.x & 0xffff0000u);
                const u32 w2 = (va.y & 0xffffu) | (vb.y << 16);
                const u32 w3 = (va.y >> 16)     | (vb.y & 0xffff0000u);
                const int rb = p4 * 4;
                *reinterpret_cast<u32*>(&sB[(rb    ) * KP + col]) = w0;
                *reinterpret_cast<u32*>(&sB[(rb + 1) * KP + col]) = w1;
                *reinterpret_cast<u32*>(&sB[(rb + 2) * KP + col]) = w2;
                *reinterpret_cast<u32*>(&sB[(rb + 3) * KP + col]) = w3;
            }
        }
        __syncthreads();

#pragma unroll
        for (int ks = 0; ks < 3; ++ks) {
            const int kof = ks * 32 + hk * 8;
            const u16* pA = &sA[r * KP + kof];
            const int rowb = wave * 32 + r;
            const int colr = (((kof >> 3) ^ ((rowb >> 2) & 3)) << 3);
            const u16* pB = &sB[rowb * KP + colr];
            const short8 a0 = *reinterpret_cast<const short8*>(pA);
            const short8 a1 = *reinterpret_cast<const short8*>(pA + 16 * KP);
            const short8 a2 = *reinterpret_cast<const short8*>(pA + 32 * KP);
            const short8 a3 = *reinterpret_cast<const short8*>(pA + 48 * KP);
            const short8 b0 = *reinterpret_cast<const short8*>(pB);
            const short8 b1 = *reinterpret_cast<const short8*>(pB + 16 * KP);
            acc[0][0] = __builtin_amdgcn_mfma_f32_16x16x32_bf16(a0, b0, acc[0][0], 0, 0, 0);
            acc[1][0] = __builtin_amdgcn_mfma_f32_16x16x32_bf16(a1, b0, acc[1][0], 0, 0, 0);
            acc[2][0] = __builtin_amdgcn_mfma_f32_16x16x32_bf16(a2, b0, acc[2][0], 0, 0, 0);
            acc[3][0] = __builtin_amdgcn_mfma_f32_16x16x32_bf16(a3, b0, acc[3][0], 0, 0, 0);
            acc[0][1] = __builtin_amdgcn_mfma_f32_16x16x32_bf16(a0, b1, acc[0][1], 0, 0, 0);
            acc[1][1] = __builtin_amdgcn_mfma_f32_16x16x32_bf16(a1, b1, acc[1][1], 0, 0, 0);
            acc[2][1] = __builtin_amdgcn_mfma_f32_16x16x32_bf16(a2, b1, acc[2][1], 0, 0, 0);
            acc[3][1] = __builtin_amdgcn_mfma_f32_16x16x32_bf16(a3, b1, acc[3][1], 0, 0, 0);
        }
        __syncthreads();
    }

#pragma unroll
    for (int mf = 0; mf < 4; ++mf) {
#pragma unroll
        for (int j = 0; j < 4; ++j) {
            const int co = co0 + mf * 16 + hk * 4 + j;
            const float bs = sBias[mf * 16 + hk * 4 + j];
            const size_t base = ((size_t)b * CDIM + co) * HWPIX + p0 + wave * 32 + r;
            Y[base]      = acc[mf][0][j] + bs;
            Y[base + 16] = acc[mf][1][j] + bs;
        }
    }
}

// ---------------------------------------------------------------------------
// Depthwise 3x3 SAME conv — 32-row tiles (halo overhead 25% -> 6.3%).
// ---------------------------------------------------------------------------
__global__ __launch_bounds__(256) void dwconv_kernel(
    const bf16* __restrict__ In, const float* __restrict__ Wd,
    const float* __restrict__ bd, bf16* __restrict__ Out)
{
    __shared__ alignas(16) u16 sIn[34 * 256];   // 17408 B
    const int bc = blockIdx.y;            // b*576 + c
    const int c = bc % C3;
    const size_t base = (size_t)bc * HWPIX;
    const int r0 = blockIdx.x * 32;
    const int tid = threadIdx.x;

    for (int idx = tid; idx < 34 * 32; idx += 256) {
        const int lr = idx >> 5, ch = idx & 31;
        const int gr = r0 + lr - 1;
        uint4 v = {0u, 0u, 0u, 0u};
        if ((unsigned)gr < IMGW)
            v = *reinterpret_cast<const uint4*>(&In[base + (size_t)gr * IMGW + ch * 8]);
        *reinterpret_cast<uint4*>(&sIn[lr * 256 + ch * 8]) = v;
    }
    __syncthreads();

    float wg[9];
#pragma unroll
    for (int t = 0; t < 9; ++t) wg[t] = Wd[c * 9 + t];

    const int rr  = tid >> 5;             // 0..7
    const int px0 = (tid & 31) * 8;
    const float bias = bd[c];

#pragma unroll
    for (int kk = 0; kk < 4; ++kk) {
        const int orow = rr + kk * 8;     // output row within tile 0..31
        float acc[8];
#pragma unroll
        for (int j = 0; j < 8; ++j) acc[j] = bias;

#pragma unroll
        for (int dy = 0; dy < 3; ++dy) {
            const u16* rp = &sIn[(orow + dy) * 256];
            const short8 mv = *reinterpret_cast<const short8*>(&rp[px0]);
            float m[8];
#pragma unroll
            for (int j = 0; j < 8; ++j) m[j] = bu2f((u16)mv[j]);
            const float lft = (px0 > 0) ? bu2f(rp[px0 - 1]) : 0.f;
            const float rgt = (px0 + 8 < 256) ? bu2f(rp[px0 + 8]) : 0.f;
            const float w0 = wg[dy * 3], w1 = wg[dy * 3 + 1], w2 = wg[dy * 3 + 2];

            acc[0] = fmaf(w0, lft, acc[0]);
            acc[0] = fmaf(w1, m[0], acc[0]);
            acc[0] = fmaf(w2, m[1], acc[0]);
#pragma unroll
            for (int j = 1; j < 7; ++j) {
                acc[j] = fmaf(w0, m[j - 1], acc[j]);
                acc[j] = fmaf(w1, m[j], acc[j]);
                acc[j] = fmaf(w2, m[j + 1], acc[j]);
            }
            acc[7] = fmaf(w0, m[6], acc[7]);
            acc[7] = fmaf(w1, m[7], acc[7]);
            acc[7] = fmaf(w2, rgt, acc[7]);
        }

        uint4 ov;
        ov.x = pack2(acc[0], acc[1]);
        ov.y = pack2(acc[2], acc[3]);
        ov.z = pack2(acc[4], acc[5]);
        ov.w = pack2(acc[6], acc[7]);
        *reinterpret_cast<uint4*>(&Out[base + (size_t)(r0 + orow) * IMGW + px0]) = ov;
    }
}

// ---------------------------------------------------------------------------
// Local (windowed 8x8) channel attention + fused global apply (unchanged).
// ---------------------------------------------------------------------------
#define CS 328          // c-row stride (u16)
#define PS 40           // row stride (u16) for sP
#define OS 36           // row stride (u16) for out-tile

__global__ __launch_bounds__(256, 3) void local_attn_kernel(
    const bf16* __restrict__ QKV, const float* __restrict__ temp,
    const float* __restrict__ Ag, u16* __restrict__ Osum)
{
    __shared__ alignas(16) u16 sMem[3 * 24 * CS];
    __shared__ float snq[4 * 32], snk[4 * 32];
    __shared__ float sAg[576];
    u16* const sQ = sMem;
    u16* const sK = sMem + 24 * CS;
    u16* const sV = sMem + 48 * CS;
    u16* const sP = sQ;     // overlay: sQ dead after Gram (barrier-protected)
    u16* const sO = sK;     // overlay: sK dead after Gram

    const int wy    = blockIdx.x >> 3;
    const int strip = blockIdx.x & 7;
    const int head  = blockIdx.y;
    const int b     = blockIdx.z;
    const int x0    = strip * 32;
    const int tid   = threadIdx.x;
    const int w     = tid >> 6;
    const int lane  = tid & 63;
    const int r     = lane & 15;
    const int hk    = lane >> 4;

    {
        const float* Asrc = Ag + ((size_t)(b * NHEADS + head)) * 576;
        for (int idx = tid; idx < 576; idx += 256) sAg[idx] = Asrc[idx];
    }

#pragma unroll
    for (int i = 0; i < 9; ++i) {
        const int idx = tid + i * 256;
        const int tensor = idx / 768;
        const int rem = idx - tensor * 768;
        const int c  = rem >> 5;
        const int rw = (rem >> 2) & 7;
        const int ch = rem & 3;
        const size_t g = ((size_t)b * C3 + tensor * CDIM + head * CPH + c) * HWPIX
                       + (size_t)(wy * 8 + rw) * IMGW + x0 + ch * 8;
        const uint4 v = *reinterpret_cast<const uint4*>(&QKV[g]);
        u16* dst = sMem + tensor * (24 * CS);
        *reinterpret_cast<uint4*>(&dst[c * CS + rw * 40 + ch * 8]) = v;
    }
    __syncthreads();

    if (tid < 192) {
        const int qk = tid / 96;
        const int rem = tid - qk * 96;
        const int ww = rem / 24, c = rem % 24;
        const u16* sT = qk ? sK : sQ;
        const int off = c * CS + ww * 8;
        float s = 0.f;
#pragma unroll
        for (int rw = 0; rw < 8; ++rw) {
            const int rw2 = (rw + c) & 7;
            const short8 v = *reinterpret_cast<const short8*>(&sT[off + rw2 * 40]);
#pragma unroll
            for (int j = 0; j < 8; ++j) {
                const float f = bu2f((u16)v[j]);
                s = fmaf(f, f, s);
            }
        }
        const float inv = 1.f / fmaxf(sqrtf(s), 1e-12f);
        if (qk) snk[ww * 32 + c] = inv; else snq[ww * 32 + c] = inv;
    }
    __syncthreads();

    f32x4 accg[2][2];
#pragma unroll
    for (int i = 0; i < 2; ++i)
#pragma unroll
        for (int j = 0; j < 2; ++j) accg[i][j] = (f32x4){0.f, 0.f, 0.f, 0.f};

#pragma unroll
    for (int kk = 0; kk < 2; ++kk) {
        const int colA = (kk * 4 + hk) * 40 + w * 8;
        const short8 aq0 = *reinterpret_cast<const short8*>(&sQ[(r     ) * CS + colA]);
        const short8 aq1 = *reinterpret_cast<const short8*>(&sQ[(16 + r) * CS + colA]);
        const short8 bk0 = *reinterpret_cast<const short8*>(&sK[(r     ) * CS + colA]);
        const short8 bk1 = *reinterpret_cast<const short8*>(&sK[(16 + r) * CS + colA]);
        accg[0][0] = __builtin_amdgcn_mfma_f32_16x16x32_bf16(aq0, bk0, accg[0][0], 0, 0, 0);
        accg[0][1] = __builtin_amdgcn_mfma_f32_16x16x32_bf16(aq0, bk1, accg[0][1], 0, 0, 0);
        accg[1][0] = __builtin_amdgcn_mfma_f32_16x16x32_bf16(aq1, bk0, accg[1][0], 0, 0, 0);
        accg[1][1] = __builtin_amdgcn_mfma_f32_16x16x32_bf16(aq1, bk1, accg[1][1], 0, 0, 0);
    }
    __syncthreads();   // all Gram reads done before sP (=sQ) writes

    const float t = temp[head];
    const int e0 = lane & 15;
    const bool v1 = e0 < 8;
    const float ink0 = snk[w * 32 + e0];
    const float ink1 = snk[w * 32 + 16 + e0];

#pragma unroll
    for (int ct = 0; ct < 2; ++ct) {
#pragma unroll
        for (int j = 0; j < 4; ++j) {
            const int cidx = ct * 16 + hk * 4 + j;
            const float inq = snq[w * 32 + (cidx < CPH ? cidx : 0)];
            const float g0 = accg[ct][0][j] * inq * ink0 * t;
            const float g1 = v1 ? accg[ct][1][j] * inq * ink1 * t : -1e30f;
            float m = fmaxf(g0, g1);
#pragma unroll
            for (int mk = 8; mk >= 1; mk >>= 1) m = fmaxf(m, __shfl_xor(m, mk));
            const float p0 = __expf(g0 - m);
            const float p1 = v1 ? __expf(g1 - m) : 0.f;
            float s = p0 + p1;
#pragma unroll
            for (int mk = 8; mk >= 1; mk >>= 1) s += __shfl_xor(s, mk);
            const float inv = 1.f / s;
            if (cidx < CPH) {
                sP[w * 32 * PS + cidx * PS + e0] = f2bu(p0 * inv + sAg[cidx * CPH + e0]);
                if (v1) sP[w * 32 * PS + cidx * PS + 16 + e0]
                    = f2bu(p1 * inv + sAg[cidx * CPH + 16 + e0]);
            }
        }
    }
    __syncthreads();

    f32x4 acco[2][4];
#pragma unroll
    for (int i = 0; i < 2; ++i)
#pragma unroll
        for (int j = 0; j < 4; ++j) acco[i][j] = (f32x4){0.f, 0.f, 0.f, 0.f};

    short8 afr[2];
#pragma unroll
    for (int ct = 0; ct < 2; ++ct) {
        if (hk < 3)
            afr[ct] = *reinterpret_cast<const short8*>(
                &sP[w * 32 * PS + (ct * 16 + r) * PS + hk * 8]);
        else
            afr[ct] = (short8){0, 0, 0, 0, 0, 0, 0, 0};
    }
#pragma unroll
    for (int nt = 0; nt < 4; ++nt) {
        const int px = nt * 16 + r;
        const int colV = (px >> 3) * 40 + w * 8 + (px & 7);
        short8 bfr;
        if (hk < 3) {
#pragma unroll
            for (int j = 0; j < 8; ++j)
                bfr[j] = (short)sV[(hk * 8 + j) * CS + colV];
        } else {
            bfr = (short8){0, 0, 0, 0, 0, 0, 0, 0};
        }
        acco[0][nt] = __builtin_amdgcn_mfma_f32_16x16x32_bf16(afr[0], bfr, acco[0][nt], 0, 0, 0);
        acco[1][nt] = __builtin_amdgcn_mfma_f32_16x16x32_bf16(afr[1], bfr, acco[1][nt], 0, 0, 0);
    }

#pragma unroll
    for (int ct = 0; ct < 2; ++ct) {
#pragma unroll
        for (int j = 0; j < 4; ++j) {
            const int cidx = ct * 16 + hk * 4 + j;
            if (cidx >= CPH) continue;
#pragma unroll
            for (int nt = 0; nt < 4; ++nt) {
                const int px = nt * 16 + r;
                const int rpx = px >> 3, pxl = px & 7;
                sO[(rpx * 24 + cidx) * OS + w * 8 + pxl] = f2bu(acco[ct][nt][j]);
            }
        }
    }
    __syncthreads();

#pragma unroll
    for (int i = 0; i < 3; ++i) {
        const int idx = tid + i * 256;     // 0..767
        const int q4 = idx & 3;
        const int row = idx >> 2;          // rpx*24 + c
        const int c = row % 24, rw = row / 24;
        const u16* src = &sO[row * OS + q4 * 8];
        const uint2 lo = *reinterpret_cast<const uint2*>(src);
        const uint2 hi = *reinterpret_cast<const uint2*>(src + 4);
        uint4 v = {lo.x, lo.y, hi.x, hi.y};
        *reinterpret_cast<uint4*>(
            &Osum[((size_t)b * CDIM + head * CPH + c) * HWPIX
                  + (size_t)(wy * 8 + rw) * IMGW + x0 + q4 * 8]) = v;
    }
}

// ---------------------------------------------------------------------------
// Global branch stats — MFMA (unchanged).
// ---------------------------------------------------------------------------
#define GRS 520

__global__ __launch_bounds__(256) void gstats_kernel(
    const bf16* __restrict__ QKV, float* __restrict__ Gp)
{
    __shared__ alignas(16) u16 sq[32 * GRS];
    __shared__ alignas(16) u16 sk[32 * GRS];

    const int chunk = blockIdx.x;        // 0..15
    const int bh = blockIdx.y;           // 0..31
    const int b = bh >> 3, head = bh & 7;
    const int tid = threadIdx.x;
    const int w = tid >> 6, lane = tid & 63;
    const int r = lane & 15, hk = lane >> 4;

    const size_t qb = ((size_t)b * C3 + head * CPH) * HWPIX;
    const size_t kb = qb + (size_t)CDIM * HWPIX;

    for (int idx = tid; idx < 1040; idx += 256) {
        const int t = idx >= 520;
        const int o = idx - t * 520;
        u16* d = (t ? sk : sq) + 24 * GRS + o * 8;
        *reinterpret_cast<uint4*>(d) = (uint4){0u, 0u, 0u, 0u};
    }

    f32x4 acc[2][2];
#pragma unroll
    for (int i = 0; i < 2; ++i)
#pragma unroll
        for (int j = 0; j < 2; ++j) acc[i][j] = (f32x4){0.f, 0.f, 0.f, 0.f};
    float nacc = 0.f;
    const int nrow = tid >> 2;
    const int nq4  = tid & 3;

    for (int st = 0; st < 8; ++st) {
        const int d0 = chunk * 4096 + st * 512;
        __syncthreads();
#pragma unroll
        for (int i = 0; i < 12; ++i) {
            const int idx = tid + i * 256;
            const int t = idx >= 1536;
            const int rem = idx - t * 1536;
            const int c = rem >> 6, dv = rem & 63;
            const uint4 v = *reinterpret_cast<const uint4*>(
                &QKV[(t ? kb : qb) + (size_t)c * HWPIX + d0 + dv * 8]);
            u16* dst = (t ? sk : sq) + c * GRS + dv * 8;
            *reinterpret_cast<uint4*>(dst) = v;
        }
        __syncthreads();

#pragma unroll
        for (int ks = 0; ks < 4; ++ks) {
            const int kof = w * 128 + ks * 32 + hk * 8;
            const short8 aq0 = *reinterpret_cast<const short8*>(&sq[(r     ) * GRS + kof]);
            const short8 aq1 = *reinterpret_cast<const short8*>(&sq[(16 + r) * GRS + kof]);
            const short8 bk0 = *reinterpret_cast<const short8*>(&sk[(r     ) * GRS + kof]);
            const short8 bk1 = *reinterpret_cast<const short8*>(&sk[(16 + r) * GRS + kof]);
            acc[0][0] = __builtin_amdgcn_mfma_f32_16x16x32_bf16(aq0, bk0, acc[0][0], 0, 0, 0);
            acc[0][1] = __builtin_amdgcn_mfma_f32_16x16x32_bf16(aq0, bk1, acc[0][1], 0, 0, 0);
            acc[1][0] = __builtin_amdgcn_mfma_f32_16x16x32_bf16(aq1, bk0, acc[1][0], 0, 0, 0);
            acc[1][1] = __builtin_amdgcn_mfma_f32_16x16x32_bf16(aq1, bk1, acc[1][1], 0, 0, 0);
        }

        if (nrow < 48) {
            const u16* rp = (nrow < 24 ? &sq[nrow * GRS] : &sk[(nrow - 24) * GRS]) + nq4 * 128;
#pragma unroll
            for (int i = 0; i < 16; ++i) {
                const short8 v = *reinterpret_cast<const short8*>(&rp[i * 8]);
#pragma unroll
                for (int j = 0; j < 8; ++j) {
                    const float f = bu2f((u16)v[j]);
                    nacc = fmaf(f, f, nacc);
                }
            }
        }
    }
    __syncthreads();

    float* red = reinterpret_cast<float*>(sq);
#pragma unroll
    for (int ct = 0; ct < 2; ++ct) {
#pragma unroll
        for (int et = 0; et < 2; ++et) {
#pragma unroll
            for (int j = 0; j < 4; ++j) {
                const int c = ct * 16 + hk * 4 + j;
                const int e = et * 16 + r;
                if (c < CPH && e < CPH)
                    red[(w * 24 + c) * 25 + e] = acc[ct][et][j];
            }
        }
    }
    __syncthreads();

    float* dst = Gp + ((size_t)bh * 32 + chunk) * 624;
    for (int idx = tid; idx < 576; idx += 256) {
        const int c = idx / 24, e = idx % 24;
        const int o = c * 25 + e;
        dst[idx] = red[o] + red[600 + o] + red[1200 + o] + red[1800 + o];
    }

    float ns = nacc;
    ns += __shfl_xor(ns, 1);
    ns += __shfl_xor(ns, 2);
    if (nrow < 48 && nq4 == 0) {
        if (nrow < 24) dst[576 + nrow] = ns;
        else           dst[600 + (nrow - 24)] = ns;
    }
}

// ---------------------------------------------------------------------------
__global__ __launch_bounds__(64) void gsoftmax_kernel(
    const float* __restrict__ Gp, const float* __restrict__ temp,
    float* __restrict__ A)
{
    __shared__ float red[624];
    const int bh = blockIdx.x, head = bh & 7;
    const int tid = threadIdx.x;

    for (int jj = tid; jj < 624; jj += 64) {
        float s = 0.f;
        for (int ch = 0; ch < 16; ++ch) s += Gp[((size_t)bh * 32 + ch) * 624 + jj];
        red[jj] = s;
    }
    __syncthreads();

    if (tid < CPH) {
        const int c = tid;
        const float t = temp[head];
        const float inq = 1.f / fmaxf(sqrtf(red[576 + c]), 1e-12f);
        float l[CPH]; float m = -1e30f;
        for (int e = 0; e < CPH; ++e) {
            const float ink = 1.f / fmaxf(sqrtf(red[600 + e]), 1e-12f);
            l[e] = red[c * CPH + e] * inq * ink * t;
            m = fmaxf(m, l[e]);
        }
        float s = 0.f;
        for (int e = 0; e < CPH; ++e) { l[e] = expf(l[e] - m); s += l[e]; }
        const float inv = 1.f / s;
        for (int e = 0; e < CPH; ++e) A[(size_t)bh * 576 + c * CPH + e] = l[e] * inv;
    }
}

// ---------------------------------------------------------------------------
extern "C" void kernel_launch(void* const* d_in, const int* in_sizes, int n_in,
                              void* d_out, int out_size, void* d_ws, size_t ws_size,
                              hipStream_t stream) {
    const float* x           = (const float*)d_in[0];
    const float* temperature = (const float*)d_in[1];
    const float* qkv_w       = (const float*)d_in[2];
    const float* qkv_b       = (const float*)d_in[3];
    const float* dw_w        = (const float*)d_in[4];
    const float* dw_b        = (const float*)d_in[5];
    const float* proj_w      = (const float*)d_in[6];
    const float* proj_b      = (const float*)d_in[7];
    float* out = (float*)d_out;

    char* ws = (char*)d_ws;
    constexpr size_t QKV_ELEMS = (size_t)NBATCH * C3 * HWPIX;
    constexpr size_t QKV_BYTES = QKV_ELEMS * sizeof(bf16);

    bf16* qkv1 = (bf16*)ws;                       // conv1x1 out (bf16)
    bf16* qkv2 = (bf16*)(ws + QKV_BYTES);         // q,k,v after depthwise (bf16)
    u16*  osum = (u16*)ws;                        // o1+o2 bf16, overlays qkv1
    float* Gp   = (float*)(ws + 2 * QKV_BYTES);   // partials
    float* Amat = Gp + (size_t)32 * 32 * 624;
    u16*  Wb    = (u16*)Gp;                       // qkv weights bf16 (dead before gstats)
    u16*  Wpb   = (u16*)(Amat + 32 * 576);        // proj weights bf16
    u16*  Xt    = (u16*)qkv2;                     // Xt overlays qkv2 (dead after conv_qkv)

    // 0. weights f32 -> bf16
    prep_weights<<<(C3 * CDIM + 255) / 256, 256, 0, stream>>>(qkv_w, Wb, C3 * CDIM);
    prep_weights<<<(CDIM * CDIM + 255) / 256, 256, 0, stream>>>(proj_w, Wpb, CDIM * CDIM);

    // 0b. X transpose+convert -> Xt
    xprep_kernel<<<dim3(HWPIX / 64, NBATCH), 256, 0, stream>>>(x, Xt);

    // 1. qkv = 1x1 conv via MFMA (global_load_lds staging)
    conv_qkv_mfma<<<9 * 512 * NBATCH, 256, 0, stream>>>(Xt, Wb, qkv_b, qkv1);

    // 2. depthwise 3x3, 32-row tiles (overwrites Xt region — Xt dead)
    dwconv_kernel<<<dim3(8, NBATCH * C3), 256, 0, stream>>>(
        qkv1, dw_w, dw_b, qkv2);

    // 3. global Gram/norm partials via MFMA (overwrites Wb — dead)
    gstats_kernel<<<dim3(16, 32), 256, 0, stream>>>(qkv2, Gp);

    // 4. reduce + softmax -> A
    gsoftmax_kernel<<<32, 64, 0, stream>>>(Gp, temperature, Amat);

    // 5. local attention + fused global apply -> osum (bf16) = o1 + o2
    local_attn_kernel<<<dim3(256, NHEADS, NBATCH), 256, 0, stream>>>(
        qkv2, temperature, Amat, osum);

    // 6. proj 1x1 conv via MFMA (bf16 osum in, f32 out)
    conv_proj_mfma<<<3 * 512 * NBATCH, 256, 0, stream>>>(osum, Wpb, proj_b, out);
}

// Round 10
// 616.719 us; speedup vs baseline: 1.0200x; 1.0200x over previous
//
#include <hip/hip_runtime.h>
#include <hip/hip_bf16.h>
#include <cstdint>
#include <cstddef>

#define HWPIX 65536
#define IMGW 256
#define CDIM 192
#define C3 576
#define NBATCH 4
#define NHEADS 8
#define CPH 24
#define KP 104   // padded K pitch (bf16 elems) for MFMA LDS tiles

using bf16 = __hip_bfloat16;
typedef __attribute__((ext_vector_type(8))) short short8;
typedef __attribute__((ext_vector_type(4))) float f32x4;
typedef unsigned int u32;
typedef unsigned short u16;

__device__ __forceinline__ float b2f(bf16 v) { return __bfloat162float(v); }
__device__ __forceinline__ bf16 f2b(float v) { return __float2bfloat16(v); }
__device__ __forceinline__ float bu2f(u16 h) { return __uint_as_float((u32)h << 16); }
__device__ __forceinline__ u16 f2bu(float x) {
    bf16 h = __float2bfloat16(x);
    return *reinterpret_cast<u16*>(&h);
}
__device__ __forceinline__ u32 pack2(float a, float b) {
    return (u32)f2bu(a) | ((u32)f2bu(b) << 16);
}

// ---------------------------------------------------------------------------
// Convert weights f32 -> bf16 (u16).
// ---------------------------------------------------------------------------
__global__ __launch_bounds__(256) void prep_weights(
    const float* __restrict__ W, u16* __restrict__ Wb, int n)
{
    int i = blockIdx.x * 256 + threadIdx.x;
    if (i < n) Wb[i] = f2bu(W[i]);
}

// ---------------------------------------------------------------------------
// X f32 [b][k][p] -> Xt bf16 [b][p][k]  (one-time transpose+convert).
// ---------------------------------------------------------------------------
__global__ __launch_bounds__(256) void xprep_kernel(
    const float* __restrict__ X, u16* __restrict__ Xt)
{
    __shared__ float sX[CDIM * 68];
    const int b  = blockIdx.y;
    const int p0 = blockIdx.x * 64;
    const int tid = threadIdx.x;

#pragma unroll
    for (int i = 0; i < 12; ++i) {
        const int idx = tid + i * 256;        // 0..3071 float4s
        const int p4 = idx & 15, k = idx >> 4;
        const float4 v = *reinterpret_cast<const float4*>(
            X + ((size_t)b * CDIM + k) * HWPIX + p0 + p4 * 4);
        *reinterpret_cast<float4*>(&sX[k * 68 + p4 * 4]) = v;
    }
    __syncthreads();

    const int p = tid >> 2;          // 0..63
    const int seg = tid & 3;         // 0..3 (6 k-blocks each)
    u16* dst = Xt + ((size_t)b * HWPIX + p0 + p) * CDIM;
#pragma unroll
    for (int s = 0; s < 6; ++s) {
        const int blk = seg * 6 + s; // 0..23, 8 k each
        float f[8];
#pragma unroll
        for (int j = 0; j < 8; ++j) f[j] = sX[(blk * 8 + j) * 68 + p];
        uint4 ov;
        ov.x = pack2(f[0], f[1]);
        ov.y = pack2(f[2], f[3]);
        ov.z = pack2(f[4], f[5]);
        ov.w = pack2(f[6], f[7]);
        *reinterpret_cast<uint4*>(dst + blk * 8) = ov;
    }
}

// ---------------------------------------------------------------------------
// qkv 1x1 conv as bf16 MFMA GEMM, reading pre-transposed Xt.
// R9 post-mortem combo: R7 staging (uint4 vector copies, KP=104, cheap
// addressing — global_load_lds's per-lane divisions doubled VALUBusy) +
// R9 epilogue (sOut stride 132: 66 dw = 2 mod 32 -> hk-rows 8 banks apart,
// vs stride-128's 8-way conflict that was ~1.65e7 of R7's 1.89e7 count).
// ---------------------------------------------------------------------------
__global__ __launch_bounds__(256, 4) void conv_qkv_mfma(
    const u16* __restrict__ Xt, const u16* __restrict__ Wb,
    const float* __restrict__ bias, bf16* __restrict__ Y)
{
    __shared__ alignas(16) u16 sA[64 * KP];
    __shared__ alignas(16) u16 sB[128 * KP];
    __shared__ float sBias[64];

    int lin = blockIdx.x;
    lin = (lin & 7) * (18432 / 8) + (lin >> 3);
    const int co_t = lin % 9;
    const int rest = lin / 9;
    const int p_t = rest & 511;
    const int b   = rest >> 9;
    const int co0 = co_t * 64;
    const int p0  = p_t * 128;

    const int tid  = threadIdx.x;
    const int wave = tid >> 6;
    const int lane = tid & 63;
    const int r  = lane & 15;
    const int hk = lane >> 4;

    if (tid < 64) sBias[tid] = bias[co0 + tid];

    f32x4 acc[4][2];
#pragma unroll
    for (int i = 0; i < 4; ++i)
#pragma unroll
        for (int j = 0; j < 2; ++j) acc[i][j] = (f32x4){0.f, 0.f, 0.f, 0.f};

#pragma unroll
    for (int c = 0; c < 2; ++c) {
        // ---- stage A: 64 co-rows x 96 k  (768 uint4, 3/thread)
        {
            int idx = tid;
#pragma unroll
            for (int i = 0; i < 3; ++i, idx += 256) {
                const int row = idx / 12, cv = idx % 12;
                const uint4 v = *reinterpret_cast<const uint4*>(
                    Wb + (size_t)(co0 + row) * CDIM + c * 96 + cv * 8);
                *reinterpret_cast<uint4*>(&sA[row * KP + cv * 8]) = v;
            }
        }
        // ---- stage B: 128 p-rows x 96 k (1536 uint4, 6/thread) — pure copy
        {
            int idx = tid;
#pragma unroll
            for (int i = 0; i < 6; ++i, idx += 256) {
                const int row = idx / 12, cv = idx % 12;
                const uint4 v = *reinterpret_cast<const uint4*>(
                    Xt + ((size_t)b * HWPIX + p0 + row) * CDIM + c * 96 + cv * 8);
                *reinterpret_cast<uint4*>(&sB[row * KP + cv * 8]) = v;
            }
        }
        __syncthreads();

#pragma unroll
        for (int ks = 0; ks < 3; ++ks) {
            const int kof = ks * 32 + hk * 8;
            const u16* pA = &sA[r * KP + kof];
            const u16* pB = &sB[(wave * 32 + r) * KP + kof];
            const short8 a0 = *reinterpret_cast<const short8*>(pA);
            const short8 a1 = *reinterpret_cast<const short8*>(pA + 16 * KP);
            const short8 a2 = *reinterpret_cast<const short8*>(pA + 32 * KP);
            const short8 a3 = *reinterpret_cast<const short8*>(pA + 48 * KP);
            const short8 b0 = *reinterpret_cast<const short8*>(pB);
            const short8 b1 = *reinterpret_cast<const short8*>(pB + 16 * KP);
            acc[0][0] = __builtin_amdgcn_mfma_f32_16x16x32_bf16(a0, b0, acc[0][0], 0, 0, 0);
            acc[1][0] = __builtin_amdgcn_mfma_f32_16x16x32_bf16(a1, b0, acc[1][0], 0, 0, 0);
            acc[2][0] = __builtin_amdgcn_mfma_f32_16x16x32_bf16(a2, b0, acc[2][0], 0, 0, 0);
            acc[3][0] = __builtin_amdgcn_mfma_f32_16x16x32_bf16(a3, b0, acc[3][0], 0, 0, 0);
            acc[0][1] = __builtin_amdgcn_mfma_f32_16x16x32_bf16(a0, b1, acc[0][1], 0, 0, 0);
            acc[1][1] = __builtin_amdgcn_mfma_f32_16x16x32_bf16(a1, b1, acc[1][1], 0, 0, 0);
            acc[2][1] = __builtin_amdgcn_mfma_f32_16x16x32_bf16(a2, b1, acc[2][1], 0, 0, 0);
            acc[3][1] = __builtin_amdgcn_mfma_f32_16x16x32_bf16(a3, b1, acc[3][1], 0, 0, 0);
        }
        __syncthreads();
    }

    // ---- epilogue: acc -> bf16 LDS tile [64co][132] -> coalesced uint4 stores
#define OS2 132
    u16* sOut = sB;   // reuse (post-barrier)
#pragma unroll
    for (int mf = 0; mf < 4; ++mf) {
#pragma unroll
        for (int j = 0; j < 4; ++j) {
            const int row = mf * 16 + hk * 4 + j;
            const float bs = sBias[row];
            sOut[row * OS2 + wave * 32 + r]      = f2bu(acc[mf][0][j] + bs);
            sOut[row * OS2 + wave * 32 + r + 16] = f2bu(acc[mf][1][j] + bs);
        }
    }
    __syncthreads();
#pragma unroll
    for (int i = 0; i < 4; ++i) {
        const int idx = tid + i * 256;
        const int row = idx >> 4, cq = idx & 15;
        const u16* src = &sOut[row * OS2 + cq * 8];
        const uint2 lo = *reinterpret_cast<const uint2*>(src);
        const uint2 hi = *reinterpret_cast<const uint2*>(src + 4);
        uint4 v = {lo.x, lo.y, hi.x, hi.y};
        *reinterpret_cast<uint4*>(
            &Y[((size_t)b * C3 + co0 + row) * HWPIX + p0 + cq * 8]) = v;
    }
}

// ---------------------------------------------------------------------------
// proj 1x1 conv as bf16 MFMA GEMM — bf16 osum [c][p] in (unchanged).
// ---------------------------------------------------------------------------
__global__ __launch_bounds__(256, 4) void conv_proj_mfma(
    const u16* __restrict__ X, const u16* __restrict__ Wb,
    const float* __restrict__ bias, float* __restrict__ Y)
{
    __shared__ alignas(16) u16 sA[64 * KP];
    __shared__ alignas(16) u16 sB[128 * KP];
    __shared__ float sBias[64];

    int lin = blockIdx.x;                       // nwg = 6144
    lin = (lin & 7) * (6144 / 8) + (lin >> 3);
    const int co_t = lin % 3;
    const int rest = lin / 3;
    const int p_t = rest & 511;
    const int b   = rest >> 9;
    const int co0 = co_t * 64;
    const int p0  = p_t * 128;

    const int tid  = threadIdx.x;
    const int wave = tid >> 6;
    const int lane = tid & 63;
    const int r  = lane & 15;
    const int hk = lane >> 4;

    if (tid < 64) sBias[tid] = bias[co0 + tid];

    f32x4 acc[4][2];
#pragma unroll
    for (int i = 0; i < 4; ++i)
#pragma unroll
        for (int j = 0; j < 2; ++j) acc[i][j] = (f32x4){0.f, 0.f, 0.f, 0.f};

    const int p4 = tid & 31;        // p-quad 0..31 (4 p each)
    const int kq = tid >> 5;        // 0..7 k-pair sub-index

#pragma unroll
    for (int c = 0; c < 2; ++c) {
        {
            int idx = tid;
#pragma unroll
            for (int i = 0; i < 3; ++i, idx += 256) {
                const int row = idx / 12, cv = idx % 12;
                const uint4 v = *reinterpret_cast<const uint4*>(
                    Wb + (size_t)(co0 + row) * CDIM + c * 96 + cv * 8);
                *reinterpret_cast<uint4*>(&sA[row * KP + cv * 8]) = v;
            }
        }
        {
            const u16* Xc = X + ((size_t)b * CDIM + c * 96) * HWPIX + p0;
#pragma unroll
            for (int i = 0; i < 6; ++i) {
                const int kp = kq + i * 8;            // 0..47
                const int k  = kp * 2;                // even
                const uint2 va = *reinterpret_cast<const uint2*>(
                    Xc + (size_t)k * HWPIX + p4 * 4);
                const uint2 vb = *reinterpret_cast<const uint2*>(
                    Xc + (size_t)(k + 1) * HWPIX + p4 * 4);
                const int col = (((kp >> 2) ^ (p4 & 3)) << 3) | (k & 7);
                const u32 w0 = (va.x & 0xffffu) | (vb.x << 16);
                const u32 w1 = (va.x >> 16)     | (vb.x & 0xffff0000u);
                const u32 w2 = (va.y & 0xffffu) | (vb.y << 16);
                const u32 w3 = (va.y >> 16)     | (vb.y & 0xffff0000u);
                const int rb = p4 * 4;
                *reinterpret_cast<u32*>(&sB[(rb    ) * KP + col]) = w0;
                *reinterpret_cast<u32*>(&sB[(rb + 1) * KP + col]) = w1;
                *reinterpret_cast<u32*>(&sB[(rb + 2) * KP + col]) = w2;
                *reinterpret_cast<u32*>(&sB[(rb + 3) * KP + col]) = w3;
            }
        }
        __syncthreads();

#pragma unroll
        for (int ks = 0; ks < 3; ++ks) {
            const int kof = ks * 32 + hk * 8;
            const u16* pA = &sA[r * KP + kof];
            const int rowb = wave * 32 + r;
            const int colr = (((kof >> 3) ^ ((rowb >> 2) & 3)) << 3);
            const u16* pB = &sB[rowb * KP + colr];
            const short8 a0 = *reinterpret_cast<const short8*>(pA);
            const short8 a1 = *reinterpret_cast<const short8*>(pA + 16 * KP);
            const short8 a2 = *reinterpret_cast<const short8*>(pA + 32 * KP);
            const short8 a3 = *reinterpret_cast<const short8*>(pA + 48 * KP);
            const short8 b0 = *reinterpret_cast<const short8*>(pB);
            const short8 b1 = *reinterpret_cast<const short8*>(pB + 16 * KP);
            acc[0][0] = __builtin_amdgcn_mfma_f32_16x16x32_bf16(a0, b0, acc[0][0], 0, 0, 0);
            acc[1][0] = __builtin_amdgcn_mfma_f32_16x16x32_bf16(a1, b0, acc[1][0], 0, 0, 0);
            acc[2][0] = __builtin_amdgcn_mfma_f32_16x16x32_bf16(a2, b0, acc[2][0], 0, 0, 0);
            acc[3][0] = __builtin_amdgcn_mfma_f32_16x16x32_bf16(a3, b0, acc[3][0], 0, 0, 0);
            acc[0][1] = __builtin_amdgcn_mfma_f32_16x16x32_bf16(a0, b1, acc[0][1], 0, 0, 0);
            acc[1][1] = __builtin_amdgcn_mfma_f32_16x16x32_bf16(a1, b1, acc[1][1], 0, 0, 0);
            acc[2][1] = __builtin_amdgcn_mfma_f32_16x16x32_bf16(a2, b1, acc[2][1], 0, 0, 0);
            acc[3][1] = __builtin_amdgcn_mfma_f32_16x16x32_bf16(a3, b1, acc[3][1], 0, 0, 0);
        }
        __syncthreads();
    }

#pragma unroll
    for (int mf = 0; mf < 4; ++mf) {
#pragma unroll
        for (int j = 0; j < 4; ++j) {
            const int co = co0 + mf * 16 + hk * 4 + j;
            const float bs = sBias[mf * 16 + hk * 4 + j];
            const size_t base = ((size_t)b * CDIM + co) * HWPIX + p0 + wave * 32 + r;
            Y[base]      = acc[mf][0][j] + bs;
            Y[base + 16] = acc[mf][1][j] + bs;
        }
    }
}

// ---------------------------------------------------------------------------
// Depthwise 3x3 SAME conv — 32-row tiles (kept from R9).
// ---------------------------------------------------------------------------
__global__ __launch_bounds__(256) void dwconv_kernel(
    const bf16* __restrict__ In, const float* __restrict__ Wd,
    const float* __restrict__ bd, bf16* __restrict__ Out)
{
    __shared__ alignas(16) u16 sIn[34 * 256];   // 17408 B
    const int bc = blockIdx.y;            // b*576 + c
    const int c = bc % C3;
    const size_t base = (size_t)bc * HWPIX;
    const int r0 = blockIdx.x * 32;
    const int tid = threadIdx.x;

    for (int idx = tid; idx < 34 * 32; idx += 256) {
        const int lr = idx >> 5, ch = idx & 31;
        const int gr = r0 + lr - 1;
        uint4 v = {0u, 0u, 0u, 0u};
        if ((unsigned)gr < IMGW)
            v = *reinterpret_cast<const uint4*>(&In[base + (size_t)gr * IMGW + ch * 8]);
        *reinterpret_cast<uint4*>(&sIn[lr * 256 + ch * 8]) = v;
    }
    __syncthreads();

    float wg[9];
#pragma unroll
    for (int t = 0; t < 9; ++t) wg[t] = Wd[c * 9 + t];

    const int rr  = tid >> 5;             // 0..7
    const int px0 = (tid & 31) * 8;
    const float bias = bd[c];

#pragma unroll
    for (int kk = 0; kk < 4; ++kk) {
        const int orow = rr + kk * 8;     // output row within tile 0..31
        float acc[8];
#pragma unroll
        for (int j = 0; j < 8; ++j) acc[j] = bias;

#pragma unroll
        for (int dy = 0; dy < 3; ++dy) {
            const u16* rp = &sIn[(orow + dy) * 256];
            const short8 mv = *reinterpret_cast<const short8*>(&rp[px0]);
            float m[8];
#pragma unroll
            for (int j = 0; j < 8; ++j) m[j] = bu2f((u16)mv[j]);
            const float lft = (px0 > 0) ? bu2f(rp[px0 - 1]) : 0.f;
            const float rgt = (px0 + 8 < 256) ? bu2f(rp[px0 + 8]) : 0.f;
            const float w0 = wg[dy * 3], w1 = wg[dy * 3 + 1], w2 = wg[dy * 3 + 2];

            acc[0] = fmaf(w0, lft, acc[0]);
            acc[0] = fmaf(w1, m[0], acc[0]);
            acc[0] = fmaf(w2, m[1], acc[0]);
#pragma unroll
            for (int j = 1; j < 7; ++j) {
                acc[j] = fmaf(w0, m[j - 1], acc[j]);
                acc[j] = fmaf(w1, m[j], acc[j]);
                acc[j] = fmaf(w2, m[j + 1], acc[j]);
            }
            acc[7] = fmaf(w0, m[6], acc[7]);
            acc[7] = fmaf(w1, m[7], acc[7]);
            acc[7] = fmaf(w2, rgt, acc[7]);
        }

        uint4 ov;
        ov.x = pack2(acc[0], acc[1]);
        ov.y = pack2(acc[2], acc[3]);
        ov.z = pack2(acc[4], acc[5]);
        ov.w = pack2(acc[6], acc[7]);
        *reinterpret_cast<uint4*>(&Out[base + (size_t)(r0 + orow) * IMGW + px0]) = ov;
    }
}

// ---------------------------------------------------------------------------
// Local (windowed 8x8) channel attention + fused global apply (unchanged).
// ---------------------------------------------------------------------------
#define CS 328          // c-row stride (u16)
#define PS 40           // row stride (u16) for sP
#define OS 36           // row stride (u16) for out-tile

__global__ __launch_bounds__(256, 3) void local_attn_kernel(
    const bf16* __restrict__ QKV, const float* __restrict__ temp,
    const float* __restrict__ Ag, u16* __restrict__ Osum)
{
    __shared__ alignas(16) u16 sMem[3 * 24 * CS];
    __shared__ float snq[4 * 32], snk[4 * 32];
    __shared__ float sAg[576];
    u16* const sQ = sMem;
    u16* const sK = sMem + 24 * CS;
    u16* const sV = sMem + 48 * CS;
    u16* const sP = sQ;     // overlay: sQ dead after Gram (barrier-protected)
    u16* const sO = sK;     // overlay: sK dead after Gram

    const int wy    = blockIdx.x >> 3;
    const int strip = blockIdx.x & 7;
    const int head  = blockIdx.y;
    const int b     = blockIdx.z;
    const int x0    = strip * 32;
    const int tid   = threadIdx.x;
    const int w     = tid >> 6;
    const int lane  = tid & 63;
    const int r     = lane & 15;
    const int hk    = lane >> 4;

    {
        const float* Asrc = Ag + ((size_t)(b * NHEADS + head)) * 576;
        for (int idx = tid; idx < 576; idx += 256) sAg[idx] = Asrc[idx];
    }

#pragma unroll
    for (int i = 0; i < 9; ++i) {
        const int idx = tid + i * 256;
        const int tensor = idx / 768;
        const int rem = idx - tensor * 768;
        const int c  = rem >> 5;
        const int rw = (rem >> 2) & 7;
        const int ch = rem & 3;
        const size_t g = ((size_t)b * C3 + tensor * CDIM + head * CPH + c) * HWPIX
                       + (size_t)(wy * 8 + rw) * IMGW + x0 + ch * 8;
        const uint4 v = *reinterpret_cast<const uint4*>(&QKV[g]);
        u16* dst = sMem + tensor * (24 * CS);
        *reinterpret_cast<uint4*>(&dst[c * CS + rw * 40 + ch * 8]) = v;
    }
    __syncthreads();

    if (tid < 192) {
        const int qk = tid / 96;
        const int rem = tid - qk * 96;
        const int ww = rem / 24, c = rem % 24;
        const u16* sT = qk ? sK : sQ;
        const int off = c * CS + ww * 8;
        float s = 0.f;
#pragma unroll
        for (int rw = 0; rw < 8; ++rw) {
            const int rw2 = (rw + c) & 7;
            const short8 v = *reinterpret_cast<const short8*>(&sT[off + rw2 * 40]);
#pragma unroll
            for (int j = 0; j < 8; ++j) {
                const float f = bu2f((u16)v[j]);
                s = fmaf(f, f, s);
            }
        }
        const float inv = 1.f / fmaxf(sqrtf(s), 1e-12f);
        if (qk) snk[ww * 32 + c] = inv; else snq[ww * 32 + c] = inv;
    }
    __syncthreads();

    f32x4 accg[2][2];
#pragma unroll
    for (int i = 0; i < 2; ++i)
#pragma unroll
        for (int j = 0; j < 2; ++j) accg[i][j] = (f32x4){0.f, 0.f, 0.f, 0.f};

#pragma unroll
    for (int kk = 0; kk < 2; ++kk) {
        const int colA = (kk * 4 + hk) * 40 + w * 8;
        const short8 aq0 = *reinterpret_cast<const short8*>(&sQ[(r     ) * CS + colA]);
        const short8 aq1 = *reinterpret_cast<const short8*>(&sQ[(16 + r) * CS + colA]);
        const short8 bk0 = *reinterpret_cast<const short8*>(&sK[(r     ) * CS + colA]);
        const short8 bk1 = *reinterpret_cast<const short8*>(&sK[(16 + r) * CS + colA]);
        accg[0][0] = __builtin_amdgcn_mfma_f32_16x16x32_bf16(aq0, bk0, accg[0][0], 0, 0, 0);
        accg[0][1] = __builtin_amdgcn_mfma_f32_16x16x32_bf16(aq0, bk1, accg[0][1], 0, 0, 0);
        accg[1][0] = __builtin_amdgcn_mfma_f32_16x16x32_bf16(aq1, bk0, accg[1][0], 0, 0, 0);
        accg[1][1] = __builtin_amdgcn_mfma_f32_16x16x32_bf16(aq1, bk1, accg[1][1], 0, 0, 0);
    }
    __syncthreads();   // all Gram reads done before sP (=sQ) writes

    const float t = temp[head];
    const int e0 = lane & 15;
    const bool v1 = e0 < 8;
    const float ink0 = snk[w * 32 + e0];
    const float ink1 = snk[w * 32 + 16 + e0];

#pragma unroll
    for (int ct = 0; ct < 2; ++ct) {
#pragma unroll
        for (int j = 0; j < 4; ++j) {
            const int cidx = ct * 16 + hk * 4 + j;
            const float inq = snq[w * 32 + (cidx < CPH ? cidx : 0)];
            const float g0 = accg[ct][0][j] * inq * ink0 * t;
            const float g1 = v1 ? accg[ct][1][j] * inq * ink1 * t : -1e30f;
            float m = fmaxf(g0, g1);
#pragma unroll
            for (int mk = 8; mk >= 1; mk >>= 1) m = fmaxf(m, __shfl_xor(m, mk));
            const float p0 = __expf(g0 - m);
            const float p1 = v1 ? __expf(g1 - m) : 0.f;
            float s = p0 + p1;
#pragma unroll
            for (int mk = 8; mk >= 1; mk >>= 1) s += __shfl_xor(s, mk);
            const float inv = 1.f / s;
            if (cidx < CPH) {
                sP[w * 32 * PS + cidx * PS + e0] = f2bu(p0 * inv + sAg[cidx * CPH + e0]);
                if (v1) sP[w * 32 * PS + cidx * PS + 16 + e0]
                    = f2bu(p1 * inv + sAg[cidx * CPH + 16 + e0]);
            }
        }
    }
    __syncthreads();

    f32x4 acco[2][4];
#pragma unroll
    for (int i = 0; i < 2; ++i)
#pragma unroll
        for (int j = 0; j < 4; ++j) acco[i][j] = (f32x4){0.f, 0.f, 0.f, 0.f};

    short8 afr[2];
#pragma unroll
    for (int ct = 0; ct < 2; ++ct) {
        if (hk < 3)
            afr[ct] = *reinterpret_cast<const short8*>(
                &sP[w * 32 * PS + (ct * 16 + r) * PS + hk * 8]);
        else
            afr[ct] = (short8){0, 0, 0, 0, 0, 0, 0, 0};
    }
#pragma unroll
    for (int nt = 0; nt < 4; ++nt) {
        const int px = nt * 16 + r;
        const int colV = (px >> 3) * 40 + w * 8 + (px & 7);
        short8 bfr;
        if (hk < 3) {
#pragma unroll
            for (int j = 0; j < 8; ++j)
                bfr[j] = (short)sV[(hk * 8 + j) * CS + colV];
        } else {
            bfr = (short8){0, 0, 0, 0, 0, 0, 0, 0};
        }
        acco[0][nt] = __builtin_amdgcn_mfma_f32_16x16x32_bf16(afr[0], bfr, acco[0][nt], 0, 0, 0);
        acco[1][nt] = __builtin_amdgcn_mfma_f32_16x16x32_bf16(afr[1], bfr, acco[1][nt], 0, 0, 0);
    }

#pragma unroll
    for (int ct = 0; ct < 2; ++ct) {
#pragma unroll
        for (int j = 0; j < 4; ++j) {
            const int cidx = ct * 16 + hk * 4 + j;
            if (cidx >= CPH) continue;
#pragma unroll
            for (int nt = 0; nt < 4; ++nt) {
                const int px = nt * 16 + r;
                const int rpx = px >> 3, pxl = px & 7;
                sO[(rpx * 24 + cidx) * OS + w * 8 + pxl] = f2bu(acco[ct][nt][j]);
            }
        }
    }
    __syncthreads();

#pragma unroll
    for (int i = 0; i < 3; ++i) {
        const int idx = tid + i * 256;     // 0..767
        const int q4 = idx & 3;
        const int row = idx >> 2;          // rpx*24 + c
        const int c = row % 24, rw = row / 24;
        const u16* src = &sO[row * OS + q4 * 8];
        const uint2 lo = *reinterpret_cast<const uint2*>(src);
        const uint2 hi = *reinterpret_cast<const uint2*>(src + 4);
        uint4 v = {lo.x, lo.y, hi.x, hi.y};
        *reinterpret_cast<uint4*>(
            &Osum[((size_t)b * CDIM + head * CPH + c) * HWPIX
                  + (size_t)(wy * 8 + rw) * IMGW + x0 + q4 * 8]) = v;
    }
}

// ---------------------------------------------------------------------------
// Global branch stats — MFMA (unchanged).
// ---------------------------------------------------------------------------
#define GRS 520

__global__ __launch_bounds__(256) void gstats_kernel(
    const bf16* __restrict__ QKV, float* __restrict__ Gp)
{
    __shared__ alignas(16) u16 sq[32 * GRS];
    __shared__ alignas(16) u16 sk[32 * GRS];

    const int chunk = blockIdx.x;        // 0..15
    const int bh = blockIdx.y;           // 0..31
    const int b = bh >> 3, head = bh & 7;
    const int tid = threadIdx.x;
    const int w = tid >> 6, lane = tid & 63;
    const int r = lane & 15, hk = lane >> 4;

    const size_t qb = ((size_t)b * C3 + head * CPH) * HWPIX;
    const size_t kb = qb + (size_t)CDIM * HWPIX;

    for (int idx = tid; idx < 1040; idx += 256) {
        const int t = idx >= 520;
        const int o = idx - t * 520;
        u16* d = (t ? sk : sq) + 24 * GRS + o * 8;
        *reinterpret_cast<uint4*>(d) = (uint4){0u, 0u, 0u, 0u};
    }

    f32x4 acc[2][2];
#pragma unroll
    for (int i = 0; i < 2; ++i)
#pragma unroll
        for (int j = 0; j < 2; ++j) acc[i][j] = (f32x4){0.f, 0.f, 0.f, 0.f};
    float nacc = 0.f;
    const int nrow = tid >> 2;
    const int nq4  = tid & 3;

    for (int st = 0; st < 8; ++st) {
        const int d0 = chunk * 4096 + st * 512;
        __syncthreads();
#pragma unroll
        for (int i = 0; i < 12; ++i) {
            const int idx = tid + i * 256;
            const int t = idx >= 1536;
            const int rem = idx - t * 1536;
            const int c = rem >> 6, dv = rem & 63;
            const uint4 v = *reinterpret_cast<const uint4*>(
                &QKV[(t ? kb : qb) + (size_t)c * HWPIX + d0 + dv * 8]);
            u16* dst = (t ? sk : sq) + c * GRS + dv * 8;
            *reinterpret_cast<uint4*>(dst) = v;
        }
        __syncthreads();

#pragma unroll
        for (int ks = 0; ks < 4; ++ks) {
            const int kof = w * 128 + ks * 32 + hk * 8;
            const short8 aq0 = *reinterpret_cast<const short8*>(&sq[(r     ) * GRS + kof]);
            const short8 aq1 = *reinterpret_cast<const short8*>(&sq[(16 + r) * GRS + kof]);
            const short8 bk0 = *reinterpret_cast<const short8*>(&sk[(r     ) * GRS + kof]);
            const short8 bk1 = *reinterpret_cast<const short8*>(&sk[(16 + r) * GRS + kof]);
            acc[0][0] = __builtin_amdgcn_mfma_f32_16x16x32_bf16(aq0, bk0, acc[0][0], 0, 0, 0);
            acc[0][1] = __builtin_amdgcn_mfma_f32_16x16x32_bf16(aq0, bk1, acc[0][1], 0, 0, 0);
            acc[1][0] = __builtin_amdgcn_mfma_f32_16x16x32_bf16(aq1, bk0, acc[1][0], 0, 0, 0);
            acc[1][1] = __builtin_amdgcn_mfma_f32_16x16x32_bf16(aq1, bk1, acc[1][1], 0, 0, 0);
        }

        if (nrow < 48) {
            const u16* rp = (nrow < 24 ? &sq[nrow * GRS] : &sk[(nrow - 24) * GRS]) + nq4 * 128;
#pragma unroll
            for (int i = 0; i < 16; ++i) {
                const short8 v = *reinterpret_cast<const short8*>(&rp[i * 8]);
#pragma unroll
                for (int j = 0; j < 8; ++j) {
                    const float f = bu2f((u16)v[j]);
                    nacc = fmaf(f, f, nacc);
                }
            }
        }
    }
    __syncthreads();

    float* red = reinterpret_cast<float*>(sq);
#pragma unroll
    for (int ct = 0; ct < 2; ++ct) {
#pragma unroll
        for (int et = 0; et < 2; ++et) {
#pragma unroll
            for (int j = 0; j < 4; ++j) {
                const int c = ct * 16 + hk * 4 + j;
                const int e = et * 16 + r;
                if (c < CPH && e < CPH)
                    red[(w * 24 + c) * 25 + e] = acc[ct][et][j];
            }
        }
    }
    __syncthreads();

    float* dst = Gp + ((size_t)bh * 32 + chunk) * 624;
    for (int idx = tid; idx < 576; idx += 256) {
        const int c = idx / 24, e = idx % 24;
        const int o = c * 25 + e;
        dst[idx] = red[o] + red[600 + o] + red[1200 + o] + red[1800 + o];
    }

    float ns = nacc;
    ns += __shfl_xor(ns, 1);
    ns += __shfl_xor(ns, 2);
    if (nrow < 48 && nq4 == 0) {
        if (nrow < 24) dst[576 + nrow] = ns;
        else           dst[600 + (nrow - 24)] = ns;
    }
}

// ---------------------------------------------------------------------------
__global__ __launch_bounds__(64) void gsoftmax_kernel(
    const float* __restrict__ Gp, const float* __restrict__ temp,
    float* __restrict__ A)
{
    __shared__ float red[624];
    const int bh = blockIdx.x, head = bh & 7;
    const int tid = threadIdx.x;

    for (int jj = tid; jj < 624; jj += 64) {
        float s = 0.f;
        for (int ch = 0; ch < 16; ++ch) s += Gp[((size_t)bh * 32 + ch) * 624 + jj];
        red[jj] = s;
    }
    __syncthreads();

    if (tid < CPH) {
        const int c = tid;
        const float t = temp[head];
        const float inq = 1.f / fmaxf(sqrtf(red[576 + c]), 1e-12f);
        float l[CPH]; float m = -1e30f;
        for (int e = 0; e < CPH; ++e) {
            const float ink = 1.f / fmaxf(sqrtf(red[600 + e]), 1e-12f);
            l[e] = red[c * CPH + e] * inq * ink * t;
            m = fmaxf(m, l[e]);
        }
        float s = 0.f;
        for (int e = 0; e < CPH; ++e) { l[e] = expf(l[e] - m); s += l[e]; }
        const float inv = 1.f / s;
        for (int e = 0; e < CPH; ++e) A[(size_t)bh * 576 + c * CPH + e] = l[e] * inv;
    }
}

// ---------------------------------------------------------------------------
extern "C" void kernel_launch(void* const* d_in, const int* in_sizes, int n_in,
                              void* d_out, int out_size, void* d_ws, size_t ws_size,
                              hipStream_t stream) {
    const float* x           = (const float*)d_in[0];
    const float* temperature = (const float*)d_in[1];
    const float* qkv_w       = (const float*)d_in[2];
    const float* qkv_b       = (const float*)d_in[3];
    const float* dw_w        = (const float*)d_in[4];
    const float* dw_b        = (const float*)d_in[5];
    const float* proj_w      = (const float*)d_in[6];
    const float* proj_b      = (const float*)d_in[7];
    float* out = (float*)d_out;

    char* ws = (char*)d_ws;
    constexpr size_t QKV_ELEMS = (size_t)NBATCH * C3 * HWPIX;
    constexpr size_t QKV_BYTES = QKV_ELEMS * sizeof(bf16);

    bf16* qkv1 = (bf16*)ws;                       // conv1x1 out (bf16)
    bf16* qkv2 = (bf16*)(ws + QKV_BYTES);         // q,k,v after depthwise (bf16)
    u16*  osum = (u16*)ws;                        // o1+o2 bf16, overlays qkv1
    float* Gp   = (float*)(ws + 2 * QKV_BYTES);   // partials
    float* Amat = Gp + (size_t)32 * 32 * 624;
    u16*  Wb    = (u16*)Gp;                       // qkv weights bf16 (dead before gstats)
    u16*  Wpb   = (u16*)(Amat + 32 * 576);        // proj weights bf16
    u16*  Xt    = (u16*)qkv2;                     // Xt overlays qkv2 (dead after conv_qkv)

    // 0. weights f32 -> bf16
    prep_weights<<<(C3 * CDIM + 255) / 256, 256, 0, stream>>>(qkv_w, Wb, C3 * CDIM);
    prep_weights<<<(CDIM * CDIM + 255) / 256, 256, 0, stream>>>(proj_w, Wpb, CDIM * CDIM);

    // 0b. X transpose+convert -> Xt
    xprep_kernel<<<dim3(HWPIX / 64, NBATCH), 256, 0, stream>>>(x, Xt);

    // 1. qkv = 1x1 conv via MFMA
    conv_qkv_mfma<<<9 * 512 * NBATCH, 256, 0, stream>>>(Xt, Wb, qkv_b, qkv1);

    // 2. depthwise 3x3, 32-row tiles (overwrites Xt region — Xt dead)
    dwconv_kernel<<<dim3(8, NBATCH * C3), 256, 0, stream>>>(
        qkv1, dw_w, dw_b, qkv2);

    // 3. global Gram/norm partials via MFMA (overwrites Wb — dead)
    gstats_kernel<<<dim3(16, 32), 256, 0, stream>>>(qkv2, Gp);

    // 4. reduce + softmax -> A
    gsoftmax_kernel<<<32, 64, 0, stream>>>(Gp, temperature, Amat);

    // 5. local attention + fused global apply -> osum (bf16) = o1 + o2
    local_attn_kernel<<<dim3(256, NHEADS, NBATCH), 256, 0, stream>>>(
        qkv2, temperature, Amat, osum);

    // 6. proj 1x1 conv via MFMA (bf16 osum in, f32 out)
    conv_proj_mfma<<<3 * 512 * NBATCH, 256, 0, stream>>>(osum, Wpb, proj_b, out);
}